// Round 2
// baseline (770.116 us; speedup 1.0000x reference)
//
#include <hip/hip_runtime.h>
#include <stdint.h>

// TreeLSTM cell fused kernel, round 2.
// BM=64 rows x BN=128 gate-cols (4 gates x 32) per block, 8 waves (4 row x 2 col).
// bf16 MFMA GEMM + LDS-transposed vectorized epilogue. 200000 = 64*3125 exactly.

typedef __attribute__((ext_vector_type(8))) short bf16x8;
typedef __attribute__((ext_vector_type(4))) float f32x4;

#define N_ROWS 200000
#define BM 64
#define BN 128
#define LDA 72          // LDS row stride in bf16 elems (64 + 8) -> balanced b128 banks
#define EPS 36          // epilogue LDS row stride in floats (32 + 4)
#define NT 512
#define MBLK 3125       // N_ROWS / BM

__device__ __forceinline__ short f2bf(float f) {
    union { float f; uint32_t u; } v; v.f = f;
    return (short)((v.u + 0x7fffu + ((v.u >> 16) & 1u)) >> 16);
}
__device__ __forceinline__ float fsig(float x) { return 1.0f / (1.0f + __expf(-x)); }
__device__ __forceinline__ float ftanh(float x) {
    float e = __expf(2.0f * x);
    return 1.0f - 2.0f / (e + 1.0f);
}
__device__ __forceinline__ bf16x8 pack8(float4 p, float4 q) {
    bf16x8 o;
    o[0] = f2bf(p.x); o[1] = f2bf(p.y); o[2] = f2bf(p.z); o[3] = f2bf(p.w);
    o[4] = f2bf(q.x); o[5] = f2bf(q.y); o[6] = f2bf(q.z); o[7] = f2bf(q.w);
    return o;
}

__global__ __launch_bounds__(NT)
void treelstm_fused(const float* __restrict__ x,
                    const float* __restrict__ Uh,
                    const float* __restrict__ fc,
                    const float* __restrict__ W_iou,
                    const float* __restrict__ b_iou,
                    const float* __restrict__ W_f,
                    const float* __restrict__ b_f,
                    float* __restrict__ out) {
    __shared__ union {
        struct { short a[BM * LDA]; short b[BN * LDA]; } g;     // 27648 B
        struct { float e0[BM * EPS]; float e1[BM * EPS]; } e;   // 18432 B
    } sm;

    const int tid  = threadIdx.x;
    const int lane = tid & 63;
    const int w    = tid >> 6;
    const int wrow = w >> 1;       // 0..3 -> rows wrow*16..+15
    const int wcol = w & 1;        // 0..1 -> B-rows wcol*64..+63

    // bijective XCD swizzle: 8 gate-siblings + consecutive mb share an XCD L2
    const int bid = blockIdx.x;
    const int p   = (bid & 7) * MBLK + (bid >> 3);
    const int mb  = p >> 3;        // 0..3124
    const int nb  = p & 7;         // gate-index block (32 gates)

    // ---------------- staging coords ----------------
    const int srow = tid >> 3;     // 0..63
    const int sch  = tid & 7;      // 0..7 (16B bf16 chunk within 64-elem row)

    const float4* pa = (const float4*)(x + (size_t)(mb * BM + srow) * 256);

    const int r1  = srow + 64;     // second B row this thread stages
    const int kg0 = nb * 32 + (srow & 31);
    const int g0  = srow >> 5;                 // 0..1 (gates i,o)
    const float4* pb0 = (const float4*)(W_iou + (size_t)(g0 * 256 + kg0) * 256);
    const float4* pb1 = (const float4*)((r1 < 96)
                        ? (W_iou + (size_t)(512 + kg0) * 256)   // gate u
                        : (W_f + (size_t)kg0 * 256));           // gate f

    f32x4 acc[4];
#pragma unroll
    for (int t = 0; t < 4; ++t) acc[t] = (f32x4){0.f, 0.f, 0.f, 0.f};

    float4 a0, a1, b00, b01, b10, b11;
    a0 = pa[2 * sch];  a1 = pa[2 * sch + 1];
    b00 = pb0[2 * sch]; b01 = pb0[2 * sch + 1];
    b10 = pb1[2 * sch]; b11 = pb1[2 * sch + 1];

    const int amrow = wrow * 16 + (lane & 15);
    const int koff  = (lane >> 4) * 8;
    const int bcol  = lane & 15;

#pragma unroll
    for (int ks = 0; ks < 4; ++ks) {
        __syncthreads();
        *(bf16x8*)&sm.g.a[srow * LDA + sch * 8] = pack8(a0, a1);
        *(bf16x8*)&sm.g.b[srow * LDA + sch * 8] = pack8(b00, b01);
        *(bf16x8*)&sm.g.b[r1 * LDA + sch * 8]   = pack8(b10, b11);
        __syncthreads();
        if (ks < 3) {
            const int o = (ks + 1) * 16;
            a0 = pa[o + 2 * sch];  a1 = pa[o + 2 * sch + 1];
            b00 = pb0[o + 2 * sch]; b01 = pb0[o + 2 * sch + 1];
            b10 = pb1[o + 2 * sch]; b11 = pb1[o + 2 * sch + 1];
        }
#pragma unroll
        for (int kk = 0; kk < 2; ++kk) {
            bf16x8 af = *(const bf16x8*)&sm.g.a[amrow * LDA + kk * 32 + koff];
#pragma unroll
            for (int t = 0; t < 4; ++t) {
                bf16x8 bfr = *(const bf16x8*)&sm.g.b[(wcol * 64 + t * 16 + bcol) * LDA + kk * 32 + koff];
                acc[t] = __builtin_amdgcn_mfma_f32_16x16x32_bf16(af, bfr, acc[t], 0, 0, 0);
            }
        }
    }

    // ---------------- epilogue (LDS transpose, float4 I/O) ----------------
    // B-row rb = wcol*64 + t*16 + bcol; gate = rb>>5 (0:i 1:o 2:u 3:f), kl = rb&31 = t01*16+bcol.
    // pass1 stages i (wcol0,t=0,1) + u (wcol1,t=0,1); pass2 stages o + f.
    const int rquad = (lane >> 4) * 4;
    float* eg = wcol ? sm.e.e1 : sm.e.e0;

    const int n  = mb * BM + srow;          // reader-owned output row
    const int kg = nb * 32 + sch * 4;       // reader-owned k (float4)
    const float* uhrow = Uh + (size_t)n * 768;
    float* out_h = out;
    float* out_c = out + (size_t)N_ROWS * 256;
    float* out_f = out + 2 * (size_t)N_ROWS * 256;
    const size_t oidx = (size_t)n * 256 + kg;

    __syncthreads();                        // all MFMA reads of sm.g done
#pragma unroll
    for (int t01 = 0; t01 < 2; ++t01)
#pragma unroll
        for (int r = 0; r < 4; ++r)
            eg[(wrow * 16 + rquad + r) * EPS + t01 * 16 + bcol] = acc[t01][r];
    __syncthreads();

    float4 vi = *(const float4*)&sm.e.e0[srow * EPS + sch * 4];
    float4 vu = *(const float4*)&sm.e.e1[srow * EPS + sch * 4];
    float4 bi = *(const float4*)&b_iou[kg];
    float4 bu = *(const float4*)&b_iou[512 + kg];
    float4 ui = *(const float4*)(uhrow + kg);
    float4 uu = *(const float4*)(uhrow + 512 + kg);
    float4 f4 = *(const float4*)(fc + (size_t)n * 256 + kg);
    float4 c;
    c.x = fsig(vi.x + bi.x + ui.x) * ftanh(vu.x + bu.x + uu.x) + f4.x;
    c.y = fsig(vi.y + bi.y + ui.y) * ftanh(vu.y + bu.y + uu.y) + f4.y;
    c.z = fsig(vi.z + bi.z + ui.z) * ftanh(vu.z + bu.z + uu.z) + f4.z;
    c.w = fsig(vi.w + bi.w + ui.w) * ftanh(vu.w + bu.w + uu.w) + f4.w;
    *(float4*)(out_c + oidx) = c;

    __syncthreads();
#pragma unroll
    for (int t01 = 0; t01 < 2; ++t01)
#pragma unroll
        for (int r = 0; r < 4; ++r)
            eg[(wrow * 16 + rquad + r) * EPS + t01 * 16 + bcol] = acc[2 + t01][r];
    __syncthreads();

    float4 vo = *(const float4*)&sm.e.e0[srow * EPS + sch * 4];
    float4 vf = *(const float4*)&sm.e.e1[srow * EPS + sch * 4];
    float4 bo = *(const float4*)&b_iou[256 + kg];
    float4 bf4 = *(const float4*)&b_f[kg];
    float4 uo = *(const float4*)(uhrow + 256 + kg);
    float4 h;
    h.x = fsig(vo.x + bo.x + uo.x) * ftanh(c.x);
    h.y = fsig(vo.y + bo.y + uo.y) * ftanh(c.y);
    h.z = fsig(vo.z + bo.z + uo.z) * ftanh(c.z);
    h.w = fsig(vo.w + bo.w + uo.w) * ftanh(c.w);
    *(float4*)(out_h + oidx) = h;
    vf.x += bf4.x; vf.y += bf4.y; vf.z += bf4.z; vf.w += bf4.w;
    *(float4*)(out_f + oidx) = vf;
}

extern "C" void kernel_launch(void* const* d_in, const int* in_sizes, int n_in,
                              void* d_out, int out_size, void* d_ws, size_t ws_size,
                              hipStream_t stream) {
    const float* x     = (const float*)d_in[0];
    const float* Uh    = (const float*)d_in[1];
    const float* fc    = (const float*)d_in[2];
    const float* W_iou = (const float*)d_in[3];
    const float* b_iou = (const float*)d_in[4];
    const float* W_f   = (const float*)d_in[5];
    const float* b_f   = (const float*)d_in[6];
    float* out = (float*)d_out;

    dim3 grid(MBLK * 8);        // 25000 blocks, %8 == 0 for bijective XCD swizzle
    dim3 block(NT);
    treelstm_fused<<<grid, block, 0, stream>>>(x, Uh, fc, W_iou, b_iou, W_f, b_f, out);
}